// Round 4
// baseline (1084.166 us; speedup 1.0000x reference)
//
#include <hip/hip_runtime.h>
#include <math.h>

#define IN_DIM 1024
#define M_DIM  256
#define R_TOT  32768          // B*S = 8*4096
#define TM     32             // rows per block
#define EPS    1e-12f
#define BSTRIDE 144           // phase-1 sB row stride (bank-rotating, validated r2)
#define PROW   1040           // sProbsHL row stride bytes: [h 512][l 512][pad 16]

// ---------------------------------------------------------------------------
// Round 4: phase-1 T14 async-STAGE split + cvt_pk conversion.
//  - Global loads for slab ks+1 issued at TOP of iteration ks (12 float4 in
//    flight across convert+2 barriers+48 MFMA; compiler emits counted
//    s_waitcnt vmcnt(12) before the convert of slab ks). Removes the naked
//    ~900-cyc HBM latency (psi) from the per-ks critical path.
//  - fp32->bf16 h/l split via v_cvt_pk_bf16_f32 (h = RTN pack, l = RTN of
//    exact residual): ~6 VALU/elem vs ~10 manual trunc. Tightens h accuracy.
// Phases 2, 3, 4 byte-identical to round 3 (validated, absmax 4.88e-4).
// ---------------------------------------------------------------------------

typedef __attribute__((ext_vector_type(8))) short s16x8;   // 8 bf16 (4 VGPRs)
typedef __attribute__((ext_vector_type(4))) float f32x4;   // MFMA accumulator

union FragU { int i[4]; int4 i4; s16x8 v; };

#define MFMA16 __builtin_amdgcn_mfma_f32_16x16x32_bf16

__device__ __forceinline__ int cvt_pk_bf16(float lo, float hi) {
    int r;
    asm("v_cvt_pk_bf16_f32 %0, %1, %2" : "=v"(r) : "v"(lo), "v"(hi));
    return r;
}
__device__ __forceinline__ unsigned short rtn_bf16(float x) {
    unsigned u = __float_as_uint(x);
    return (unsigned short)((u + 0x7FFFu + ((u >> 16) & 1u)) >> 16);
}

__global__ __launch_bounds__(256, 3) void povm_kernel(
    const float* __restrict__ psi_re, const float* __restrict__ psi_im,
    const float* __restrict__ basis_re, const float* __restrict__ basis_im,
    float* __restrict__ out,
    long long off_im,       // float offset of imag plane (== off_probs if none)
    long long off_probs,    // float offset of probs chunk
    long long cap)          // total float capacity (= out_size)
{
    __shared__ __align__(16) char sMem[M_DIM * BSTRIDE]; // 36864 B: ph1 B-tile, then sProbsHL
    __shared__ float sRS[4][TM];                         // ph2 rowsums; ph3 nsq partials
    __shared__ float sScale[TM];

    const int tid  = threadIdx.x;
    const int lane = tid & 63;
    const int w    = tid >> 6;          // wave 0..3
    const int g    = lane >> 4;         // 0..3 (k-group)
    const int h16  = lane & 15;         // row (A) / col (B,C) within tile
    const int row0 = blockIdx.x * TM;
    const int mw   = w * 64;            // phase-1 m-slab

    // staging ids (phase 1): thread covers (m = it*64 + (tid>>2), i-quad = tid&3)
    const int sq  = tid & 3;
    const int smb = tid >> 2;

    f32x4 accRe[2][4], accIm[2][4];
    #pragma unroll
    for (int rt = 0; rt < 2; ++rt)
        #pragma unroll
        for (int ct = 0; ct < 4; ++ct) {
            accRe[rt][ct] = (f32x4){0.f, 0.f, 0.f, 0.f};
            accIm[rt][ct] = (f32x4){0.f, 0.f, 0.f, 0.f};
        }

    // ===================== phase 1: inner GEMM via MFMA, T14-pipelined =====================
    float4 car[2], cai[2], cbr[4], cbi[4];
    // prologue: issue slab-0 loads
    {
        #pragma unroll
        for (int rt = 0; rt < 2; ++rt) {
            const size_t off = (size_t)(row0 + rt * 16 + h16) * IN_DIM + g * 4;
            car[rt] = *(const float4*)(psi_re + off);
            cai[rt] = *(const float4*)(psi_im + off);
        }
        #pragma unroll
        for (int it = 0; it < 4; ++it) {
            const size_t boff = (size_t)(it * 64 + smb) * IN_DIM + sq * 4;
            cbr[it] = *(const float4*)(basis_re + boff);
            cbi[it] = *(const float4*)(basis_im + boff);
        }
    }

    for (int ks = 0; ks < 64; ++ks) {
        // ---- issue next-slab loads FIRST (stay in flight across this iter) ----
        float4 nar[2], nai[2], nbr[4], nbi[4];
        if (ks < 63) {
            const int ibn = (ks + 1) * 16;
            #pragma unroll
            for (int rt = 0; rt < 2; ++rt) {
                const size_t off = (size_t)(row0 + rt * 16 + h16) * IN_DIM + ibn + g * 4;
                nar[rt] = *(const float4*)(psi_re + off);
                nai[rt] = *(const float4*)(psi_im + off);
            }
            #pragma unroll
            for (int it = 0; it < 4; ++it) {
                const size_t boff = (size_t)(it * 64 + smb) * IN_DIM + ibn + sq * 4;
                nbr[it] = *(const float4*)(basis_re + boff);
                nbi[it] = *(const float4*)(basis_im + boff);
            }
        }

        // ---- stage basis slab (cur regs) -> bf16 h/l LDS ----
        #pragma unroll
        for (int it = 0; it < 4; ++it) {
            FragU hf, lf;
            #pragma unroll
            for (int d = 0; d < 4; ++d) {
                const float re = (&cbr[it].x)[d], im = (&cbi[it].x)[d];
                const int wh = cvt_pk_bf16(re, im);
                const float reh = __uint_as_float(((unsigned)wh) << 16);
                const float imh = __uint_as_float(((unsigned)wh) & 0xFFFF0000u);
                hf.i[d] = wh;
                lf.i[d] = cvt_pk_bf16(re - reh, im - imh);
            }
            char* rowp = sMem + (it * 64 + smb) * BSTRIDE;
            *(int4*)(rowp + 16 * sq)      = hf.i4;   // h half: bytes [0,64)
            *(int4*)(rowp + 64 + 16 * sq) = lf.i4;   // l half: bytes [64,128)
        }

        // ---- build A fragments from cur psi regs ----
        s16x8 a1h[2], a1l[2], a2h[2], a2l[2];
        #pragma unroll
        for (int rt = 0; rt < 2; ++rt) {
            FragU fh, fl, gh, gl;
            #pragma unroll
            for (int d = 0; d < 4; ++d) {
                const float re = (&car[rt].x)[d], im = (&cai[rt].x)[d];
                const int wh = cvt_pk_bf16(re, im);
                const float reh = __uint_as_float(((unsigned)wh) << 16);
                const float imh = __uint_as_float(((unsigned)wh) & 0xFFFF0000u);
                const int wl = cvt_pk_bf16(re - reh, im - imh);
                fh.i[d] = wh; fl.i[d] = wl;
                // A2 = [im, -re]: rotate 16 then negate new high half
                const unsigned x = (unsigned)wh;
                gh.i[d] = (int)(((x >> 16) | (x << 16)) ^ 0x80000000u);
                const unsigned y = (unsigned)wl;
                gl.i[d] = (int)(((y >> 16) | (y << 16)) ^ 0x80000000u);
            }
            a1h[rt] = fh.v; a1l[rt] = fl.v;
            a2h[rt] = gh.v; a2l[rt] = gl.v;
        }
        __syncthreads();

        // ---- B frags from LDS + 48 MFMA ----
        #pragma unroll
        for (int ct = 0; ct < 4; ++ct) {
            const char* rowp = sMem + (mw + ct * 16 + h16) * BSTRIDE;
            const s16x8 bh = *(const s16x8*)(rowp + 16 * g);
            const s16x8 bl = *(const s16x8*)(rowp + 64 + 16 * g);
            #pragma unroll
            for (int rt = 0; rt < 2; ++rt) {
                accRe[rt][ct] = MFMA16(a1h[rt], bh, accRe[rt][ct], 0, 0, 0);
                accRe[rt][ct] = MFMA16(a1h[rt], bl, accRe[rt][ct], 0, 0, 0);
                accRe[rt][ct] = MFMA16(a1l[rt], bh, accRe[rt][ct], 0, 0, 0);
                accIm[rt][ct] = MFMA16(a2h[rt], bh, accIm[rt][ct], 0, 0, 0);
                accIm[rt][ct] = MFMA16(a2h[rt], bl, accIm[rt][ct], 0, 0, 0);
                accIm[rt][ct] = MFMA16(a2l[rt], bh, accIm[rt][ct], 0, 0, 0);
            }
        }
        __syncthreads();

        if (ks < 63) {
            #pragma unroll
            for (int rt = 0; rt < 2; ++rt) { car[rt] = nar[rt]; cai[rt] = nai[rt]; }
            #pragma unroll
            for (int it = 0; it < 4; ++it) { cbr[it] = nbr[it]; cbi[it] = nbi[it]; }
        }
    }

    // ===================== phase 2: p = |inner|^2, probs =====================
    float rs[2][4];
    #pragma unroll
    for (int rt = 0; rt < 2; ++rt)
        #pragma unroll
        for (int q = 0; q < 4; ++q) rs[rt][q] = 0.f;
    #pragma unroll
    for (int rt = 0; rt < 2; ++rt)
        #pragma unroll
        for (int ct = 0; ct < 4; ++ct)
            #pragma unroll
            for (int q = 0; q < 4; ++q) {
                const float p = accRe[rt][ct][q] * accRe[rt][ct][q] +
                                accIm[rt][ct][q] * accIm[rt][ct][q];
                accRe[rt][ct][q] = p;
                rs[rt][q] += p;
            }
    #pragma unroll
    for (int off = 1; off < 16; off <<= 1) {
        #pragma unroll
        for (int rt = 0; rt < 2; ++rt)
            #pragma unroll
            for (int q = 0; q < 4; ++q)
                rs[rt][q] += __shfl_xor(rs[rt][q], off, 64);
    }
    if (h16 == 0) {
        #pragma unroll
        for (int rt = 0; rt < 2; ++rt)
            #pragma unroll
            for (int q = 0; q < 4; ++q)
                sRS[w][rt * 16 + g * 4 + q] = rs[rt][q];
    }
    __syncthreads();
    float inv[2][4];
    #pragma unroll
    for (int rt = 0; rt < 2; ++rt)
        #pragma unroll
        for (int q = 0; q < 4; ++q) {
            const int R = rt * 16 + g * 4 + q;
            inv[rt][q] = 1.f / (sRS[0][R] + sRS[1][R] + sRS[2][R] + sRS[3][R] + EPS);
        }
    // store probs fp32 to global + bf16 h/l to sProbsHL (aliases dead ph1 tile)
    #pragma unroll
    for (int rt = 0; rt < 2; ++rt)
        #pragma unroll
        for (int ct = 0; ct < 4; ++ct)
            #pragma unroll
            for (int q = 0; q < 4; ++q) {
                const float p = accRe[rt][ct][q] * inv[rt][q];
                const int R  = rt * 16 + g * 4 + q;
                const int Mc = mw + ct * 16 + h16;
                const unsigned short ph = rtn_bf16(p);
                const float phf = __uint_as_float((unsigned)ph << 16);
                const unsigned short pl = rtn_bf16(p - phf);
                *(unsigned short*)(sMem + R * PROW + 2 * Mc)       = ph;
                *(unsigned short*)(sMem + R * PROW + 512 + 2 * Mc) = pl;
                const long long po = off_probs + (long long)(row0 + R) * M_DIM + Mc;
                if (po < cap) out[po] = p;
            }
    __syncthreads();

    // ===================== phase 3: collapsed = probs @ basis via MFMA =====================
    {
        const int wi0 = w * 256;            // wave-private i range: no barriers in loop
        float nsqp[2][4];
        #pragma unroll
        for (int rt = 0; rt < 2; ++rt)
            #pragma unroll
            for (int q = 0; q < 4; ++q) nsqp[rt][q] = 0.f;

        for (int ibk = 0; ibk < 4; ++ibk) {
            const int ibase = wi0 + ibk * 64;
            f32x4 cRe[2][4], cIm[2][4];
            #pragma unroll
            for (int rt = 0; rt < 2; ++rt)
                #pragma unroll
                for (int nt = 0; nt < 4; ++nt) {
                    cRe[rt][nt] = (f32x4){0.f, 0.f, 0.f, 0.f};
                    cIm[rt][nt] = (f32x4){0.f, 0.f, 0.f, 0.f};
                }
            for (int ks = 0; ks < 8; ++ks) {
                s16x8 ah[2], al[2];
                #pragma unroll
                for (int rt = 0; rt < 2; ++rt) {
                    const char* rp = sMem + (rt * 16 + h16) * PROW + ks * 64 + 16 * g;
                    ah[rt] = *(const s16x8*)(rp);
                    al[rt] = *(const s16x8*)(rp + 512);
                }
                const int mrow = ks * 32 + 8 * g;       // k-slot base: matches A-frag k map
                #pragma unroll
                for (int nt = 0; nt < 4; ++nt) {
                    const int col = ibase + nt * 16 + h16;
                    const float* pr = basis_re + (size_t)mrow * IN_DIM + col;
                    const float* pi = basis_im + (size_t)mrow * IN_DIM + col;
                    FragU bR, bI;
                    #pragma unroll
                    for (int d = 0; d < 4; ++d) {
                        bR.i[d] = cvt_pk_bf16(pr[(size_t)(2 * d) * IN_DIM],
                                              pr[(size_t)(2 * d + 1) * IN_DIM]);
                        bI.i[d] = cvt_pk_bf16(pi[(size_t)(2 * d) * IN_DIM],
                                              pi[(size_t)(2 * d + 1) * IN_DIM]);
                    }
                    #pragma unroll
                    for (int rt = 0; rt < 2; ++rt) {
                        cRe[rt][nt] = MFMA16(ah[rt], bR.v, cRe[rt][nt], 0, 0, 0);
                        cRe[rt][nt] = MFMA16(al[rt], bR.v, cRe[rt][nt], 0, 0, 0);
                        cIm[rt][nt] = MFMA16(ah[rt], bI.v, cIm[rt][nt], 0, 0, 0);
                        cIm[rt][nt] = MFMA16(al[rt], bI.v, cIm[rt][nt], 0, 0, 0);
                    }
                }
            }
            // epilogue: nsq partials + unscaled store (C layout: row=4g+q, col=h16)
            #pragma unroll
            for (int rt = 0; rt < 2; ++rt)
                #pragma unroll
                for (int nt = 0; nt < 4; ++nt) {
                    const int col = ibase + nt * 16 + h16;
                    #pragma unroll
                    for (int q = 0; q < 4; ++q) {
                        const float vr = cRe[rt][nt][q], vi = cIm[rt][nt][q];
                        nsqp[rt][q] += vr * vr + vi * vi;
                        const int row = rt * 16 + 4 * g + q;
                        const long long o = (long long)(row0 + row) * IN_DIM + col;
                        if (o < off_im) out[o] = vr;
                        const long long oi = off_im + o;
                        if (oi < off_probs) out[oi] = vi;
                    }
                }
        }
        // reduce nsq over the 16 h16 lanes; publish per-wave partials
        #pragma unroll
        for (int off = 1; off < 16; off <<= 1) {
            #pragma unroll
            for (int rt = 0; rt < 2; ++rt)
                #pragma unroll
                for (int q = 0; q < 4; ++q)
                    nsqp[rt][q] += __shfl_xor(nsqp[rt][q], off, 64);
        }
        if (h16 == 0) {
            #pragma unroll
            for (int rt = 0; rt < 2; ++rt)
                #pragma unroll
                for (int q = 0; q < 4; ++q)
                    sRS[w][rt * 16 + 4 * g + q] = nsqp[rt][q];
        }
        __syncthreads();
        if (tid < TM)
            sScale[tid] = 1.f / (sqrtf(sRS[0][tid] + sRS[1][tid] +
                                       sRS[2][tid] + sRS[3][tid]) + EPS);
        __syncthreads();
    }

    // ===================== phase 4: rescale own writes (unchanged) =====================
    {
        const int tr = tid >> 5;
        const int tm = tid & 31;
        for (int ic = 0; ic < 4; ++ic) {
            const int i0 = ic * 256 + 8 * tm;
            #pragma unroll
            for (int a = 0; a < 4; ++a) {
                const int row = 4 * tr + a;
                const float s = sScale[row];
                const long long o = (long long)(row0 + row) * IN_DIM + i0;
                if (o + 8 <= off_im) {
                    #pragma unroll
                    for (int q = 0; q < 2; ++q) {
                        float4 v = *(float4*)(out + o + 4 * q);
                        v.x *= s; v.y *= s; v.z *= s; v.w *= s;
                        *(float4*)(out + o + 4 * q) = v;
                    }
                }
                const long long oi = off_im + o;
                if (oi + 8 <= off_probs) {
                    #pragma unroll
                    for (int q = 0; q < 2; ++q) {
                        float4 vw = *(float4*)(out + oi + 4 * q);
                        vw.x *= s; vw.y *= s; vw.z *= s; vw.w *= s;
                        *(float4*)(out + oi + 4 * q) = vw;
                    }
                }
            }
        }
    }
}

extern "C" void kernel_launch(void* const* d_in, const int* in_sizes, int n_in,
                              void* d_out, int out_size, void* d_ws, size_t ws_size,
                              hipStream_t stream)
{
    const float* psi_re   = (const float*)d_in[0];
    const float* psi_im   = (const float*)d_in[1];
    const float* basis_re = (const float*)d_in[2];
    const float* basis_im = (const float*)d_in[3];

    const long long RIN = (long long)R_TOT * IN_DIM;   // 33,554,432
    const long long RM  = (long long)R_TOT * M_DIM;    //  8,388,608
    const long long cap = (long long)out_size;

    long long off_im, off_probs;
    if (cap == 2 * RIN + RM) {            // planar re/im + probs (75,497,472)
        off_im = RIN; off_probs = 2 * RIN;
    } else if (cap == RIN + RM) {         // real-part-only + probs (41,943,040)
        off_im = RIN; off_probs = RIN;    // imag region width 0 -> guards skip
    } else {                              // fallback: derived planar split
        long long plane = (cap - RM) / 2;
        if (plane < 0) plane = 0;
        off_im = plane; off_probs = 2 * plane;
    }

    povm_kernel<<<R_TOT / TM, 256, 0, stream>>>(psi_re, psi_im, basis_re, basis_im,
                                                (float*)d_out, off_im, off_probs, cap);
}

// Round 5
// 893.254 us; speedup vs baseline: 1.2137x; 1.2137x over previous
//
#include <hip/hip_runtime.h>
#include <math.h>

#define IN_DIM 1024
#define M_DIM  256
#define R_TOT  32768          // B*S = 8*4096
#define TM     32             // rows per block
#define EPS    1e-12f
#define BSTRIDE 144           // phase-1 sB row stride (bank-rotating, validated r2)
#define PROW   1040           // sProbsHL row stride bytes: [h 512][l 512][pad 16]

// ---------------------------------------------------------------------------
// Round 5: correct phase-1 pipeline (T4-lite).
//  - r4 failed because __syncthreads() drains vmcnt(0): prefetched loads were
//    forcibly completed at the first barrier (+ conditional prefetch spilled).
//  - Fix: prefetch next slab UNCONDITIONALLY (clamped index, branchless) and
//    replace in-loop __syncthreads with {s_waitcnt lgkmcnt(0); s_barrier} —
//    LDS ordering preserved, but the 12 wave-private global loads stay in
//    flight across both barriers (whole-iteration cover for ~900cyc HBM lat).
//    Legal: phase 1 has no global stores; loads target private registers.
//  - cvt_pk_bf16 conversions kept from r4 (absmax-verified).
// Phases 2, 3, 4 byte-identical to round 3 (validated, absmax 4.88e-4).
// ---------------------------------------------------------------------------

typedef __attribute__((ext_vector_type(8))) short s16x8;   // 8 bf16 (4 VGPRs)
typedef __attribute__((ext_vector_type(4))) float f32x4;   // MFMA accumulator

union FragU { int i[4]; int4 i4; s16x8 v; };

#define MFMA16 __builtin_amdgcn_mfma_f32_16x16x32_bf16

__device__ __forceinline__ int cvt_pk_bf16(float lo, float hi) {
    int r;
    asm("v_cvt_pk_bf16_f32 %0, %1, %2" : "=v"(r) : "v"(lo), "v"(hi));
    return r;
}
__device__ __forceinline__ unsigned short rtn_bf16(float x) {
    unsigned u = __float_as_uint(x);
    return (unsigned short)((u + 0x7FFFu + ((u >> 16) & 1u)) >> 16);
}

__global__ __launch_bounds__(256) void povm_kernel(
    const float* __restrict__ psi_re, const float* __restrict__ psi_im,
    const float* __restrict__ basis_re, const float* __restrict__ basis_im,
    float* __restrict__ out,
    long long off_im,       // float offset of imag plane (== off_probs if none)
    long long off_probs,    // float offset of probs chunk
    long long cap)          // total float capacity (= out_size)
{
    __shared__ __align__(16) char sMem[M_DIM * BSTRIDE]; // 36864 B: ph1 B-tile, then sProbsHL
    __shared__ float sRS[4][TM];                         // ph2 rowsums; ph3 nsq partials
    __shared__ float sScale[TM];

    const int tid  = threadIdx.x;
    const int lane = tid & 63;
    const int w    = tid >> 6;          // wave 0..3
    const int g    = lane >> 4;         // 0..3 (k-group)
    const int h16  = lane & 15;         // row (A) / col (B,C) within tile
    const int row0 = blockIdx.x * TM;
    const int mw   = w * 64;            // phase-1 m-slab

    // staging ids (phase 1): thread covers (m = it*64 + (tid>>2), i-quad = tid&3)
    const int sq  = tid & 3;
    const int smb = tid >> 2;

    f32x4 accRe[2][4], accIm[2][4];
    #pragma unroll
    for (int rt = 0; rt < 2; ++rt)
        #pragma unroll
        for (int ct = 0; ct < 4; ++ct) {
            accRe[rt][ct] = (f32x4){0.f, 0.f, 0.f, 0.f};
            accIm[rt][ct] = (f32x4){0.f, 0.f, 0.f, 0.f};
        }

    // ===================== phase 1: inner GEMM via MFMA, pipelined =====================
    float4 car[2], cai[2], cbr[4], cbi[4];
    // prologue: issue slab-0 loads
    {
        #pragma unroll
        for (int rt = 0; rt < 2; ++rt) {
            const size_t off = (size_t)(row0 + rt * 16 + h16) * IN_DIM + g * 4;
            car[rt] = *(const float4*)(psi_re + off);
            cai[rt] = *(const float4*)(psi_im + off);
        }
        #pragma unroll
        for (int it = 0; it < 4; ++it) {
            const size_t boff = (size_t)(it * 64 + smb) * IN_DIM + sq * 4;
            cbr[it] = *(const float4*)(basis_re + boff);
            cbi[it] = *(const float4*)(basis_im + boff);
        }
    }

    for (int ks = 0; ks < 64; ++ks) {
        // ---- issue next-slab loads FIRST, unconditionally (clamped index) ----
        const int ibn = (ks < 63 ? ks + 1 : 63) * 16;
        float4 nar[2], nai[2], nbr[4], nbi[4];
        #pragma unroll
        for (int rt = 0; rt < 2; ++rt) {
            const size_t off = (size_t)(row0 + rt * 16 + h16) * IN_DIM + ibn + g * 4;
            nar[rt] = *(const float4*)(psi_re + off);
            nai[rt] = *(const float4*)(psi_im + off);
        }
        #pragma unroll
        for (int it = 0; it < 4; ++it) {
            const size_t boff = (size_t)(it * 64 + smb) * IN_DIM + ibn + sq * 4;
            nbr[it] = *(const float4*)(basis_re + boff);
            nbi[it] = *(const float4*)(basis_im + boff);
        }

        // ---- stage cur basis slab -> bf16 h/l LDS (cvt_pk) ----
        #pragma unroll
        for (int it = 0; it < 4; ++it) {
            FragU hf, lf;
            #pragma unroll
            for (int d = 0; d < 4; ++d) {
                const float re = (&cbr[it].x)[d], im = (&cbi[it].x)[d];
                const int wh = cvt_pk_bf16(re, im);
                const float reh = __uint_as_float(((unsigned)wh) << 16);
                const float imh = __uint_as_float(((unsigned)wh) & 0xFFFF0000u);
                hf.i[d] = wh;
                lf.i[d] = cvt_pk_bf16(re - reh, im - imh);
            }
            char* rowp = sMem + (it * 64 + smb) * BSTRIDE;
            *(int4*)(rowp + 16 * sq)      = hf.i4;   // h half: bytes [0,64)
            *(int4*)(rowp + 64 + 16 * sq) = lf.i4;   // l half: bytes [64,128)
        }

        // ---- build A fragments from cur psi regs (register-only) ----
        s16x8 a1h[2], a1l[2], a2h[2], a2l[2];
        #pragma unroll
        for (int rt = 0; rt < 2; ++rt) {
            FragU fh, fl, gh, gl;
            #pragma unroll
            for (int d = 0; d < 4; ++d) {
                const float re = (&car[rt].x)[d], im = (&cai[rt].x)[d];
                const int wh = cvt_pk_bf16(re, im);
                const float reh = __uint_as_float(((unsigned)wh) << 16);
                const float imh = __uint_as_float(((unsigned)wh) & 0xFFFF0000u);
                const int wl = cvt_pk_bf16(re - reh, im - imh);
                fh.i[d] = wh; fl.i[d] = wl;
                // A2 = [im, -re]: rotate 16 then negate new high half
                const unsigned x = (unsigned)wh;
                gh.i[d] = (int)(((x >> 16) | (x << 16)) ^ 0x80000000u);
                const unsigned y = (unsigned)wl;
                gl.i[d] = (int)(((y >> 16) | (y << 16)) ^ 0x80000000u);
            }
            a1h[rt] = fh.v; a1l[rt] = fl.v;
            a2h[rt] = gh.v; a2l[rt] = gl.v;
        }

        // LDS-only drain + raw barrier: prefetched global loads stay in flight
        asm volatile("s_waitcnt lgkmcnt(0)" ::: "memory");
        __builtin_amdgcn_s_barrier();

        // ---- B frags from LDS + 48 MFMA ----
        #pragma unroll
        for (int ct = 0; ct < 4; ++ct) {
            const char* rowp = sMem + (mw + ct * 16 + h16) * BSTRIDE;
            const s16x8 bh = *(const s16x8*)(rowp + 16 * g);
            const s16x8 bl = *(const s16x8*)(rowp + 64 + 16 * g);
            #pragma unroll
            for (int rt = 0; rt < 2; ++rt) {
                accRe[rt][ct] = MFMA16(a1h[rt], bh, accRe[rt][ct], 0, 0, 0);
                accRe[rt][ct] = MFMA16(a1h[rt], bl, accRe[rt][ct], 0, 0, 0);
                accRe[rt][ct] = MFMA16(a1l[rt], bh, accRe[rt][ct], 0, 0, 0);
                accIm[rt][ct] = MFMA16(a2h[rt], bh, accIm[rt][ct], 0, 0, 0);
                accIm[rt][ct] = MFMA16(a2h[rt], bl, accIm[rt][ct], 0, 0, 0);
                accIm[rt][ct] = MFMA16(a2l[rt], bh, accIm[rt][ct], 0, 0, 0);
            }
        }

        // reads complete (compiler lgkmcnt before MFMA); protect LDS reuse
        __builtin_amdgcn_s_barrier();

        #pragma unroll
        for (int rt = 0; rt < 2; ++rt) { car[rt] = nar[rt]; cai[rt] = nai[rt]; }
        #pragma unroll
        for (int it = 0; it < 4; ++it) { cbr[it] = nbr[it]; cbi[it] = nbi[it]; }
    }

    // ===================== phase 2: p = |inner|^2, probs =====================
    float rs[2][4];
    #pragma unroll
    for (int rt = 0; rt < 2; ++rt)
        #pragma unroll
        for (int q = 0; q < 4; ++q) rs[rt][q] = 0.f;
    #pragma unroll
    for (int rt = 0; rt < 2; ++rt)
        #pragma unroll
        for (int ct = 0; ct < 4; ++ct)
            #pragma unroll
            for (int q = 0; q < 4; ++q) {
                const float p = accRe[rt][ct][q] * accRe[rt][ct][q] +
                                accIm[rt][ct][q] * accIm[rt][ct][q];
                accRe[rt][ct][q] = p;
                rs[rt][q] += p;
            }
    #pragma unroll
    for (int off = 1; off < 16; off <<= 1) {
        #pragma unroll
        for (int rt = 0; rt < 2; ++rt)
            #pragma unroll
            for (int q = 0; q < 4; ++q)
                rs[rt][q] += __shfl_xor(rs[rt][q], off, 64);
    }
    if (h16 == 0) {
        #pragma unroll
        for (int rt = 0; rt < 2; ++rt)
            #pragma unroll
            for (int q = 0; q < 4; ++q)
                sRS[w][rt * 16 + g * 4 + q] = rs[rt][q];
    }
    __syncthreads();
    float inv[2][4];
    #pragma unroll
    for (int rt = 0; rt < 2; ++rt)
        #pragma unroll
        for (int q = 0; q < 4; ++q) {
            const int R = rt * 16 + g * 4 + q;
            inv[rt][q] = 1.f / (sRS[0][R] + sRS[1][R] + sRS[2][R] + sRS[3][R] + EPS);
        }
    // store probs fp32 to global + bf16 h/l to sProbsHL (aliases dead ph1 tile)
    #pragma unroll
    for (int rt = 0; rt < 2; ++rt)
        #pragma unroll
        for (int ct = 0; ct < 4; ++ct)
            #pragma unroll
            for (int q = 0; q < 4; ++q) {
                const float p = accRe[rt][ct][q] * inv[rt][q];
                const int R  = rt * 16 + g * 4 + q;
                const int Mc = mw + ct * 16 + h16;
                const unsigned short ph = rtn_bf16(p);
                const float phf = __uint_as_float((unsigned)ph << 16);
                const unsigned short pl = rtn_bf16(p - phf);
                *(unsigned short*)(sMem + R * PROW + 2 * Mc)       = ph;
                *(unsigned short*)(sMem + R * PROW + 512 + 2 * Mc) = pl;
                const long long po = off_probs + (long long)(row0 + R) * M_DIM + Mc;
                if (po < cap) out[po] = p;
            }
    __syncthreads();

    // ===================== phase 3: collapsed = probs @ basis via MFMA =====================
    {
        const int wi0 = w * 256;            // wave-private i range: no barriers in loop
        float nsqp[2][4];
        #pragma unroll
        for (int rt = 0; rt < 2; ++rt)
            #pragma unroll
            for (int q = 0; q < 4; ++q) nsqp[rt][q] = 0.f;

        for (int ibk = 0; ibk < 4; ++ibk) {
            const int ibase = wi0 + ibk * 64;
            f32x4 cRe[2][4], cIm[2][4];
            #pragma unroll
            for (int rt = 0; rt < 2; ++rt)
                #pragma unroll
                for (int nt = 0; nt < 4; ++nt) {
                    cRe[rt][nt] = (f32x4){0.f, 0.f, 0.f, 0.f};
                    cIm[rt][nt] = (f32x4){0.f, 0.f, 0.f, 0.f};
                }
            for (int ks = 0; ks < 8; ++ks) {
                s16x8 ah[2], al[2];
                #pragma unroll
                for (int rt = 0; rt < 2; ++rt) {
                    const char* rp = sMem + (rt * 16 + h16) * PROW + ks * 64 + 16 * g;
                    ah[rt] = *(const s16x8*)(rp);
                    al[rt] = *(const s16x8*)(rp + 512);
                }
                const int mrow = ks * 32 + 8 * g;       // k-slot base: matches A-frag k map
                #pragma unroll
                for (int nt = 0; nt < 4; ++nt) {
                    const int col = ibase + nt * 16 + h16;
                    const float* pr = basis_re + (size_t)mrow * IN_DIM + col;
                    const float* pi = basis_im + (size_t)mrow * IN_DIM + col;
                    FragU bR, bI;
                    #pragma unroll
                    for (int d = 0; d < 4; ++d) {
                        bR.i[d] = cvt_pk_bf16(pr[(size_t)(2 * d) * IN_DIM],
                                              pr[(size_t)(2 * d + 1) * IN_DIM]);
                        bI.i[d] = cvt_pk_bf16(pi[(size_t)(2 * d) * IN_DIM],
                                              pi[(size_t)(2 * d + 1) * IN_DIM]);
                    }
                    #pragma unroll
                    for (int rt = 0; rt < 2; ++rt) {
                        cRe[rt][nt] = MFMA16(ah[rt], bR.v, cRe[rt][nt], 0, 0, 0);
                        cRe[rt][nt] = MFMA16(al[rt], bR.v, cRe[rt][nt], 0, 0, 0);
                        cIm[rt][nt] = MFMA16(ah[rt], bI.v, cIm[rt][nt], 0, 0, 0);
                        cIm[rt][nt] = MFMA16(al[rt], bI.v, cIm[rt][nt], 0, 0, 0);
                    }
                }
            }
            // epilogue: nsq partials + unscaled store (C layout: row=4g+q, col=h16)
            #pragma unroll
            for (int rt = 0; rt < 2; ++rt)
                #pragma unroll
                for (int nt = 0; nt < 4; ++nt) {
                    const int col = ibase + nt * 16 + h16;
                    #pragma unroll
                    for (int q = 0; q < 4; ++q) {
                        const float vr = cRe[rt][nt][q], vi = cIm[rt][nt][q];
                        nsqp[rt][q] += vr * vr + vi * vi;
                        const int row = rt * 16 + 4 * g + q;
                        const long long o = (long long)(row0 + row) * IN_DIM + col;
                        if (o < off_im) out[o] = vr;
                        const long long oi = off_im + o;
                        if (oi < off_probs) out[oi] = vi;
                    }
                }
        }
        // reduce nsq over the 16 h16 lanes; publish per-wave partials
        #pragma unroll
        for (int off = 1; off < 16; off <<= 1) {
            #pragma unroll
            for (int rt = 0; rt < 2; ++rt)
                #pragma unroll
                for (int q = 0; q < 4; ++q)
                    nsqp[rt][q] += __shfl_xor(nsqp[rt][q], off, 64);
        }
        if (h16 == 0) {
            #pragma unroll
            for (int rt = 0; rt < 2; ++rt)
                #pragma unroll
                for (int q = 0; q < 4; ++q)
                    sRS[w][rt * 16 + 4 * g + q] = nsqp[rt][q];
        }
        __syncthreads();
        if (tid < TM)
            sScale[tid] = 1.f / (sqrtf(sRS[0][tid] + sRS[1][tid] +
                                       sRS[2][tid] + sRS[3][tid]) + EPS);
        __syncthreads();
    }

    // ===================== phase 4: rescale own writes (unchanged) =====================
    {
        const int tr = tid >> 5;
        const int tm = tid & 31;
        for (int ic = 0; ic < 4; ++ic) {
            const int i0 = ic * 256 + 8 * tm;
            #pragma unroll
            for (int a = 0; a < 4; ++a) {
                const int row = 4 * tr + a;
                const float s = sScale[row];
                const long long o = (long long)(row0 + row) * IN_DIM + i0;
                if (o + 8 <= off_im) {
                    #pragma unroll
                    for (int q = 0; q < 2; ++q) {
                        float4 v = *(float4*)(out + o + 4 * q);
                        v.x *= s; v.y *= s; v.z *= s; v.w *= s;
                        *(float4*)(out + o + 4 * q) = v;
                    }
                }
                const long long oi = off_im + o;
                if (oi + 8 <= off_probs) {
                    #pragma unroll
                    for (int q = 0; q < 2; ++q) {
                        float4 vw = *(float4*)(out + oi + 4 * q);
                        vw.x *= s; vw.y *= s; vw.z *= s; vw.w *= s;
                        *(float4*)(out + oi + 4 * q) = vw;
                    }
                }
            }
        }
    }
}

extern "C" void kernel_launch(void* const* d_in, const int* in_sizes, int n_in,
                              void* d_out, int out_size, void* d_ws, size_t ws_size,
                              hipStream_t stream)
{
    const float* psi_re   = (const float*)d_in[0];
    const float* psi_im   = (const float*)d_in[1];
    const float* basis_re = (const float*)d_in[2];
    const float* basis_im = (const float*)d_in[3];

    const long long RIN = (long long)R_TOT * IN_DIM;   // 33,554,432
    const long long RM  = (long long)R_TOT * M_DIM;    //  8,388,608
    const long long cap = (long long)out_size;

    long long off_im, off_probs;
    if (cap == 2 * RIN + RM) {            // planar re/im + probs (75,497,472)
        off_im = RIN; off_probs = 2 * RIN;
    } else if (cap == RIN + RM) {         // real-part-only + probs (41,943,040)
        off_im = RIN; off_probs = RIN;    // imag region width 0 -> guards skip
    } else {                              // fallback: derived planar split
        long long plane = (cap - RM) / 2;
        if (plane < 0) plane = 0;
        off_im = plane; off_probs = 2 * plane;
    }

    povm_kernel<<<R_TOT / TM, 256, 0, stream>>>(psi_re, psi_im, basis_re, basis_im,
                                                (float*)d_out, off_im, off_probs, cap);
}